// Round 4
// baseline (225.389 us; speedup 1.0000x reference)
//
#include <hip/hip_runtime.h>

// ---------- common helpers ----------
typedef __attribute__((ext_vector_type(8))) unsigned short ushort8v;
typedef __attribute__((ext_vector_type(8))) __bf16 bf16x8;
typedef __attribute__((ext_vector_type(4))) float floatx4;

__device__ __forceinline__ unsigned short f2b(float f) {
    unsigned u = __float_as_uint(f);
    unsigned r = u + 0x7fffu + ((u >> 16) & 1u);   // RNE
    return (unsigned short)(r >> 16);
}
__device__ __forceinline__ float b2f(unsigned short h) {
    return __uint_as_float(((unsigned)h) << 16);
}

__device__ __forceinline__ void async_cp16(const void* g, void* l) {
    __builtin_amdgcn_global_load_lds(
        (__attribute__((address_space(1))) void*)g,
        (__attribute__((address_space(3))) void*)l,
        16, 0, 0);
}

// ---------- fused prep: cvt x (16384 blocks) | transpose_W (2048) | softmax (1024) ----------
__global__ __launch_bounds__(256) void prep_kernel(const float* __restrict__ x,
                                                   unsigned short* __restrict__ xb,
                                                   const float* __restrict__ W,
                                                   unsigned short* __restrict__ Wt,
                                                   const float* __restrict__ ld_,
                                                   unsigned short* __restrict__ P) {
    __shared__ float tile[32 * 33];
    __shared__ float buf[1000];
    __shared__ float red[8];
    const int b = blockIdx.x, t = threadIdx.x;
    if (b < 16384) {                       // ---- cvt x fp32 -> bf16 (float4) ----
        int i = b * 256 + t;
        float4 v = ((const float4*)x)[i];
        ushort4 o;
        o.x = f2b(v.x); o.y = f2b(v.y); o.z = f2b(v.z); o.w = f2b(v.w);
        ((ushort4*)xb)[i] = o;
    } else if (b < 16384 + 2048) {         // ---- W (2048x1023) -> Wt (1024x2048 bf16) ----
        int idx = b - 16384;
        int n0 = (idx & 31) * 32, k0 = (idx >> 5) * 32;
        int tx = t & 31, ty = t >> 5;
#pragma unroll
        for (int i = 0; i < 4; i++) {
            int k = k0 + ty + i * 8, n = n0 + tx;
            tile[(ty + i * 8) * 33 + tx] = (n < 1023) ? W[(size_t)k * 1023 + n] : 0.f;
        }
        __syncthreads();
#pragma unroll
        for (int i = 0; i < 4; i++) {
            int n = n0 + ty + i * 8, k = k0 + tx;
            Wt[(size_t)n * 2048 + k] = f2b(tile[tx * 33 + ty + i * 8]);
        }
    } else {                               // ---- softmax rows of leaf_dist -> P bf16 ----
        int row = b - 18432;
        const float* r = ld_ + (size_t)row * 1000;
        float mx = -3.4e38f;
        for (int i = t; i < 1000; i += 256) { float v = r[i]; buf[i] = v; mx = fmaxf(mx, v); }
#pragma unroll
        for (int o = 32; o > 0; o >>= 1) mx = fmaxf(mx, __shfl_down(mx, o));
        if ((t & 63) == 0) red[t >> 6] = mx;
        __syncthreads();
        mx = fmaxf(fmaxf(red[0], red[1]), fmaxf(red[2], red[3]));
        float s = 0.f;
        for (int i = t; i < 1000; i += 256) { float e = __expf(buf[i] - mx); buf[i] = e; s += e; }
#pragma unroll
        for (int o = 32; o > 0; o >>= 1) s += __shfl_down(s, o);
        if ((t & 63) == 0) red[4 + (t >> 6)] = s;
        __syncthreads();
        float inv = 1.f / (red[4] + red[5] + red[6] + red[7]);
        unsigned short* out = P + (size_t)row * 1000;
        for (int i = t; i < 1000; i += 256) out[i] = f2b(buf[i] * inv);
    }
}

// ---------- fused: pp tree routing (8192 blocks) | transpose_P (1024 blocks) ----------
__global__ __launch_bounds__(256) void pp_transP_kernel(unsigned short* __restrict__ dec,
                                                        const unsigned short* __restrict__ P,
                                                        unsigned short* __restrict__ Pt) {
    __shared__ float smem[3072];           // pp: d|pa|pb ; transP: ushort tile[32][33]
    const int b = blockIdx.x, t = threadIdx.x;
    if (b < 8192) {                        // ---- pp: literal reference recurrence ----
        float* d = smem; float* pa = smem + 1024; float* pb = smem + 2048;
        unsigned short* row = dec + (size_t)b * 1024;
        for (int i = t; i < 1024; i += 256) d[i] = (i < 1023) ? b2f(row[i]) : 0.f;
        if (t == 0) pa[0] = 1.f;
        __syncthreads();
        float* cur = pa; float* nxt = pb;
        for (int dep = 0; dep < 10; dep++) {
            const int half = 1 << dep;
            const int len = half << 1;
            for (int j = t; j < len; j += 256) {
                int tt = j >> dep;
                int s  = j & (half - 1);
                int i2 = 2 * s + tt;
                int u  = i2 >> dep;
                int rr = i2 & (half - 1);
                float dv = d[half - 1 + rr];
                nxt[j] = cur[rr] * (u ? (1.f - dv) : dv);
            }
            __syncthreads();
            float* tmp = cur; cur = nxt; nxt = tmp;
        }
        for (int i = t; i < 1024; i += 256) row[i] = f2b(cur[i]);
    } else {                               // ---- P (1024x1000) -> Pt (1024x1024), zero-pad ----
        int idx = b - 8192;
        int c0 = (idx & 31) * 32, l0 = (idx >> 5) * 32;
        int tx = t & 31, ty = t >> 5;
        unsigned short* tile = (unsigned short*)smem;
#pragma unroll
        for (int i = 0; i < 4; i++) {
            int c = c0 + tx, l = l0 + ty + i * 8;
            tile[(ty + i * 8) * 33 + tx] = (c < 1000) ? P[(size_t)l * 1000 + c] : (unsigned short)0;
        }
        __syncthreads();
#pragma unroll
        for (int i = 0; i < 4; i++) {
            Pt[(size_t)(c0 + ty + i * 8) * 1024 + l0 + tx] = tile[tx * 33 + ty + i * 8];
        }
    }
}

// ---------- bf16 GEMM: latency-restructured K-loop ----------
// R3 post-mortem: MfmaUtil 22%, VALUBusy 18%, HBM 10% -> pure latency-bound;
// each BK=32 iter exposed one full load-drain (~575 cyc effective). Fix:
//  * LDS double-buffer + ONE barrier/iter, ordered issue(next) -> compute(cur)
//    -> barrier, so the vmcnt(0) drain is covered by own ds_read+MFMA.
//  * BK=64: half the barriers, 2x compute per drain. LDS 48KB -> 3 blocks/CU.
// XOR swizzle for 128B rows: phys 16B-chunk p = logical c ^ (row&7);
// fragment ds_read_b128 -> 2 lanes/bank (free, m136).
// XCD swizzle: xcd g owns bm-tiles [16g,16g+16) for all bn (A fetched once/XCD).
#define BM 64
#define BN 128
#define BK 64

template <int EPI>
__global__ __launch_bounds__(256, 3) void gemm_bt(const unsigned short* __restrict__ A,
                                                  const unsigned short* __restrict__ Bt,
                                                  const float* __restrict__ bias,
                                                  unsigned short* __restrict__ obf,
                                                  float* __restrict__ of32,
                                                  int K, int ldo) {
    __shared__ __align__(16) unsigned short As[2][BM * BK];   // 2 x 8 KB
    __shared__ __align__(16) unsigned short Bs[2][BN * BK];   // 2 x 16 KB
    const int tid  = threadIdx.x;
    const int lane = tid & 63;
    const int wave = tid >> 6;
    const int wrow = (wave >> 1) * 32;     // wave covers 32 rows x 64 cols
    const int wcol = (wave & 1) * 64;
    const int quad = lane >> 4, l16 = lane & 15;

    // XCD-aware decode: 1024 blocks = 128 bm-tiles x 8 bn-tiles
    const int l   = blockIdx.x;
    const int xcd = l & 7;
    const int j   = l >> 3;                    // 0..127
    const int bm  = (xcd * 16 + (j & 15)) * BM;
    const int bn  = (j >> 4) * BN;

    // ---- staging map: each wave owns A-chunks [2w,2w+2), B-chunks [4w,4w+4);
    // chunk c = 1KB = rows 8c..8c+8 (128B each). Lane: row 8c+(l>>3), phys 16B
    // chunk l&7 holds logical chunk (l&7)^(row&7).
    const int lr = lane >> 3;                  // row within chunk
    const int lc = lane & 7;                   // physical 16B chunk
    const int ce = (lc ^ lr) * 8;              // logical element offset in row
    size_t aoff[2], boff[4];
#pragma unroll
    for (int ja = 0; ja < 2; ja++)
        aoff[ja] = (size_t)(bm + 16 * wave + 8 * ja + lr) * K + ce;
#pragma unroll
    for (int jb = 0; jb < 4; jb++)
        boff[jb] = (size_t)(bn + 32 * wave + 8 * jb + lr) * K + ce;

    // ---- fragment-read swizzled k offsets (elements), row&7 == l16&7
    const int rA  = l16 & 7;
    const int ka0 = (quad ^ rA) * 8;           // kk=0: logical chunk quad
    const int ka1 = ((quad + 4) ^ rA) * 8;     // kk=1: logical chunk quad+4

    floatx4 acc[2][4] = {};

    // prologue: stage buf 0
    {
        char* ab = (char*)As[0];
        char* bb = (char*)Bs[0];
#pragma unroll
        for (int ja = 0; ja < 2; ja++) async_cp16(A + aoff[ja], ab + (2 * wave + ja) * 1024);
#pragma unroll
        for (int jb = 0; jb < 4; jb++) async_cp16(Bt + boff[jb], bb + (4 * wave + jb) * 1024);
    }
    __syncthreads();

    const int NIT = K >> 6;
    for (int it = 0; it < NIT; it++) {
        const int cur = it & 1;
        if (it + 1 < NIT) {                    // prefetch next buf BEFORE compute
            const int k0 = (it + 1) << 6;
            char* ab = (char*)As[cur ^ 1];
            char* bb = (char*)Bs[cur ^ 1];
#pragma unroll
            for (int ja = 0; ja < 2; ja++)
                async_cp16(A + aoff[ja] + k0, ab + (2 * wave + ja) * 1024);
#pragma unroll
            for (int jb = 0; jb < 4; jb++)
                async_cp16(Bt + boff[jb] + k0, bb + (4 * wave + jb) * 1024);
        }

        const unsigned short* as = As[cur];
        const unsigned short* bs = Bs[cur];
        bf16x8 af[2][2], bfr[2][4];
#pragma unroll
        for (int mi = 0; mi < 2; mi++) {
            const unsigned short* rp = as + (wrow + mi * 16 + l16) * BK;
            af[0][mi] = __builtin_bit_cast(bf16x8, *(const ushort8v*)(rp + ka0));
            af[1][mi] = __builtin_bit_cast(bf16x8, *(const ushort8v*)(rp + ka1));
        }
#pragma unroll
        for (int ni = 0; ni < 4; ni++) {
            const unsigned short* rp = bs + (wcol + ni * 16 + l16) * BK;
            bfr[0][ni] = __builtin_bit_cast(bf16x8, *(const ushort8v*)(rp + ka0));
            bfr[1][ni] = __builtin_bit_cast(bf16x8, *(const ushort8v*)(rp + ka1));
        }
#pragma unroll
        for (int kk = 0; kk < 2; kk++)
#pragma unroll
            for (int mi = 0; mi < 2; mi++)
#pragma unroll
                for (int ni = 0; ni < 4; ni++)
                    acc[mi][ni] = __builtin_amdgcn_mfma_f32_16x16x32_bf16(
                        af[kk][mi], bfr[kk][ni], acc[mi][ni], 0, 0, 0);
        __syncthreads();   // single barrier: drains prefetch (covered by compute
                           // above) and protects cur-buf from next overwrite
    }

#pragma unroll
    for (int ni = 0; ni < 4; ni++) {
        const int col = bn + wcol + ni * 16 + l16;
        float bb = 0.f;
        if constexpr (EPI == 0) bb = (col < 1023) ? bias[col] : 0.f;
#pragma unroll
        for (int mi = 0; mi < 2; mi++) {
            const int row0 = bm + wrow + mi * 16 + quad * 4;
#pragma unroll
            for (int r = 0; r < 4; r++) {
                float v = acc[mi][ni][r];
                if constexpr (EPI == 0) {
                    float sgm = 1.f / (1.f + __expf(-(v + bb)));
                    obf[(size_t)(row0 + r) * ldo + col] = f2b(sgm);
                } else {
                    if (col < 1000) of32[(size_t)(row0 + r) * ldo + col] = v;
                }
            }
        }
    }
}

// ---------- host ----------
extern "C" void kernel_launch(void* const* d_in, const int* in_sizes, int n_in,
                              void* d_out, int out_size, void* d_ws, size_t ws_size,
                              hipStream_t stream) {
    const float* x   = (const float*)d_in[0];   // 8192x2048
    const float* W   = (const float*)d_in[1];   // 2048x1023
    const float* b   = (const float*)d_in[2];   // 1023
    const float* ldd = (const float*)d_in[3];   // 1024x1000
    float* out = (float*)d_out;                 // 8192x1000

    char* ws = (char*)d_ws;
    unsigned short* xb  = (unsigned short*)(ws);              // 8192x2048 bf16
    unsigned short* Wt  = (unsigned short*)(ws + 33554432);   // 1024x2048 bf16
    unsigned short* dec = (unsigned short*)(ws + 37748736);   // 8192x1024 bf16 (in-place pp)
    unsigned short* P   = (unsigned short*)(ws + 54525952);   // 1024x1000 bf16
    unsigned short* Pt  = (unsigned short*)(ws + 56574208);   // 1024x1024 bf16

    // prep: cvt | transpose_W | softmax  (independent, one launch)
    prep_kernel<<<16384 + 2048 + 1024, 256, 0, stream>>>(x, xb, W, Wt, ldd, P);
    // decisions = sigmoid(x@W + b), padded to 1024 cols
    gemm_bt<0><<<1024, 256, 0, stream>>>(xb, Wt, b, dec, nullptr, 2048, 1024);
    // pp (reference-literal order, in place) | transpose_P  (independent, one launch)
    pp_transP_kernel<<<8192 + 1024, 256, 0, stream>>>(dec, P, Pt);
    // out = pp @ P
    gemm_bt<1><<<1024, 256, 0, stream>>>(dec, Pt, nullptr, nullptr, out, 1024, 1000);
}